// Round 8
// baseline (10403.700 us; speedup 1.0000x reference)
//
#include <hip/hip_runtime.h>

typedef _Float16 f16;
typedef __attribute__((ext_vector_type(4))) _Float16 f16x4;
typedef __attribute__((ext_vector_type(8))) _Float16 f16x8;
typedef __attribute__((ext_vector_type(4))) float f32x4;
typedef __attribute__((ext_vector_type(16))) float f32x16;

#define HID 512
#define DIMS_X 16
#define NSTEPS 127
#define BM 128
#define BATCH 32768

// ws f16 layout offsets (elements)
#define OFF_W0 0
#define OFF_W1 32768
#define OFF_W2 (32768 + 262144)
#define OFF_W3 (32768 + 2 * 262144)
#define OFF_W4 (32768 + 3 * 262144)

// Pack f32 row-major [K][N] weights into f16 fragment-linear [Kpad/8][N][8].
__global__ void pack_w_kernel(const float* __restrict__ w, f16* __restrict__ out,
                              int K, int Kpad, int N) {
    int idx = blockIdx.x * blockDim.x + threadIdx.x;
    if (idx >= Kpad * N) return;
    int k = idx / N, n = idx - k * N;
    float v = (k < K) ? w[k * N + n] : 0.0f;
    out[(((k >> 3) * N) + n) * 8 + (k & 7)] = (f16)v;
}

// W0 pack with input-row permutation to the kernel's input layout:
// new rows 0-15 = x_t (orig 1..16), 16-31 = x_1 (orig 17..32), 32 = t (orig 0), 33-63 = 0.
__global__ void pack_w0_kernel(const float* __restrict__ w, f16* __restrict__ out) {
    int idx = blockIdx.x * blockDim.x + threadIdx.x;
    if (idx >= 64 * HID) return;
    int kn = idx / HID, n = idx - kn * HID;
    float v;
    if (kn < 32) v = w[(kn + 1) * HID + n];
    else if (kn == 32) v = w[n];
    else v = 0.0f;
    out[(((kn >> 3) * HID) + n) * 8 + (kn & 7)] = (f16)v;
}

__device__ __forceinline__ unsigned rotl32(unsigned x, int r) {
    return (x << r) | (x >> (32 - r));
}

// Threefry-2x32-20, matching jax._src.prng.threefry2x32 exactly.
__device__ __forceinline__ void threefry2x32(unsigned k0, unsigned k1,
                                             unsigned c0, unsigned c1,
                                             unsigned& o0, unsigned& o1) {
    unsigned ks2 = k0 ^ k1 ^ 0x1BD11BDAu;
    unsigned x0 = c0 + k0, x1 = c1 + k1;
#define TF_R(rot) { x0 += x1; x1 = rotl32(x1, rot); x1 ^= x0; }
    TF_R(13) TF_R(15) TF_R(26) TF_R(6)
    x0 += k1;  x1 += ks2 + 1u;
    TF_R(17) TF_R(29) TF_R(16) TF_R(24)
    x0 += ks2; x1 += k0 + 2u;
    TF_R(13) TF_R(15) TF_R(26) TF_R(6)
    x0 += k0;  x1 += k1 + 3u;
    TF_R(17) TF_R(29) TF_R(16) TF_R(24)
    x0 += k1;  x1 += ks2 + 4u;
    TF_R(13) TF_R(15) TF_R(26) TF_R(6)
    x0 += ks2; x1 += k0 + 5u;
#undef TF_R
    o0 = x0; o1 = x1;
}

// XLA's f32 ErfInv expansion (Giles polynomial).
__device__ __forceinline__ float erfinv_xla(float x) {
    float w = -log1pf(-x * x);
    float p;
    if (w < 5.0f) {
        w = w - 2.5f;
        p = 2.81022636e-08f;
        p = fmaf(p, w, 3.43273939e-07f);
        p = fmaf(p, w, -3.5233877e-06f);
        p = fmaf(p, w, -4.39150654e-06f);
        p = fmaf(p, w, 0.00021858087f);
        p = fmaf(p, w, -0.00125372503f);
        p = fmaf(p, w, -0.00417768164f);
        p = fmaf(p, w, 0.246640727f);
        p = fmaf(p, w, 1.50140941f);
    } else {
        w = sqrtf(w) - 3.0f;
        p = -0.000200214257f;
        p = fmaf(p, w, 0.000100950558f);
        p = fmaf(p, w, 0.00134934322f);
        p = fmaf(p, w, -0.00367342844f);
        p = fmaf(p, w, 0.00573950773f);
        p = fmaf(p, w, -0.0076224613f);
        p = fmaf(p, w, 0.00943887047f);
        p = fmaf(p, w, 1.00167406f);
        p = fmaf(p, w, 2.83297682f);
    }
    return p * x;
}

// LDS byte offset, 32-stripe XOR swizzle on a [BM][512] f16 tile.
__device__ __forceinline__ unsigned lds_off(int row, int colByte) {
    return (unsigned)(row * 1024 + (colByte ^ ((row & 31) << 4)));
}

// 8 MFMAs of one kc (16 k-elems), B-frags read inline (rows tb*32+l31 -> row&31 == l31).
__device__ __forceinline__ void kc_mfma8(f32x16 (&acc)[2][4], const f16* act,
                                         const f16x8& w0, const f16x8& w1,
                                         int kc, int l31, int kh) {
    unsigned colPart = (unsigned)((kc * 32 + kh * 16) ^ (l31 << 4));
    f16x8 b0 = *(const f16x8*)((const char*)act + (unsigned)((0 * 32 + l31) * 1024) + colPart);
    f16x8 b1 = *(const f16x8*)((const char*)act + (unsigned)((1 * 32 + l31) * 1024) + colPart);
    f16x8 b2 = *(const f16x8*)((const char*)act + (unsigned)((2 * 32 + l31) * 1024) + colPart);
    f16x8 b3 = *(const f16x8*)((const char*)act + (unsigned)((3 * 32 + l31) * 1024) + colPart);
    acc[0][0] = __builtin_amdgcn_mfma_f32_32x32x16_f16(w0, b0, acc[0][0], 0, 0, 0);
    acc[0][1] = __builtin_amdgcn_mfma_f32_32x32x16_f16(w0, b1, acc[0][1], 0, 0, 0);
    acc[0][2] = __builtin_amdgcn_mfma_f32_32x32x16_f16(w0, b2, acc[0][2], 0, 0, 0);
    acc[0][3] = __builtin_amdgcn_mfma_f32_32x32x16_f16(w0, b3, acc[0][3], 0, 0, 0);
    acc[1][0] = __builtin_amdgcn_mfma_f32_32x32x16_f16(w1, b0, acc[1][0], 0, 0, 0);
    acc[1][1] = __builtin_amdgcn_mfma_f32_32x32x16_f16(w1, b1, acc[1][1], 0, 0, 0);
    acc[1][2] = __builtin_amdgcn_mfma_f32_32x32x16_f16(w1, b2, acc[1][2], 0, 0, 0);
    acc[1][3] = __builtin_amdgcn_mfma_f32_32x32x16_f16(w1, b3, acc[1][3], 0, 0, 0);
}

__device__ __forceinline__ void init_acc(f32x16 (&acc)[2][4], const float* bias_l,
                                         int wv, int kh) {
#pragma unroll
    for (int t = 0; t < 2; ++t) {
        f32x4 bq0 = *(const f32x4*)(bias_l + wv * 64 + t * 32 + 0 + kh * 4);
        f32x4 bq1 = *(const f32x4*)(bias_l + wv * 64 + t * 32 + 8 + kh * 4);
        f32x4 bq2 = *(const f32x4*)(bias_l + wv * 64 + t * 32 + 16 + kh * 4);
        f32x4 bq3 = *(const f32x4*)(bias_l + wv * 64 + t * 32 + 24 + kh * 4);
        f32x16 bv;
#pragma unroll
        for (int r = 0; r < 4; ++r) {
            bv[r] = bq0[r]; bv[4 + r] = bq1[r]; bv[8 + r] = bq2[r]; bv[12 + r] = bq3[r];
        }
#pragma unroll
        for (int tb = 0; tb < 4; ++tb) acc[t][tb] = bv;
    }
}

// Epilogue: relu(acc) -> f16 -> own 64 cols, all 128 rows (D frag: col=l31 batch row,
// reg (q,r): hidden col = t*32 + q*8 + kh*4 + r).
__device__ __forceinline__ void epi_relu(f32x16 (&acc)[2][4], f16* act,
                                         int wv, int l31, int kh) {
#pragma unroll
    for (int t = 0; t < 2; ++t)
#pragma unroll
        for (int tb = 0; tb < 4; ++tb) {
            int b = tb * 32 + l31;
#pragma unroll
            for (int q = 0; q < 4; ++q) {
                f16x4 v;
#pragma unroll
                for (int r = 0; r < 4; ++r)
                    v[r] = (f16)fmaxf(acc[t][tb][4 * q + r], 0.0f);
                int nb = (wv * 64 + t * 32 + q * 8 + kh * 4) * 2;
                *(f16x4*)((char*)act + lds_off(b, nb)) = v;
            }
        }
}

// Issue next layer's weights for this wave's own 4 kc (kc = wv4..wv4+3).
__device__ __forceinline__ void load_w4(f16x8 (&wE)[8], const f16* __restrict__ Wp,
                                        int wv4, int l31, int kh) {
    const f16* wbase = Wp + ((size_t)kh * HID + wv4 * 16 + l31) * 8;
#pragma unroll
    for (int j = 0; j < 4; ++j) {
        const f16* wk = wbase + (size_t)(wv4 + j) * 8192;
        wE[2 * j] = *(const f16x8*)wk;
        wE[2 * j + 1] = *(const f16x8*)(wk + 256);
    }
}

// Early compute: first 4 kc of next layer on this wave's SELF-WRITTEN cols
// (runs before the end-of-layer barrier; no cross-wave data needed).
__device__ __forceinline__ void early4(f32x16 (&acc)[2][4], const f16* act,
                                       const f16x8 (&wE)[8], int wv4, int l31, int kh) {
#pragma unroll
    for (int j = 0; j < 4; ++j)
        kc_mfma8(acc, act, wE[2 * j], wE[2 * j + 1], wv4 + j, l31, kh);
}

// Rotated main loop: j = 4..31, kc = (wv4+j)&31 (starts right after own cols -> the
// first reads after the barrier hit freshly-written neighbor cols, no cold start).
__device__ __forceinline__ void hidden_main(f32x16 (&acc)[2][4], const f16* act,
                                            const f16* __restrict__ Wp,
                                            int wv4, int l31, int kh) {
    const f16* wbase = Wp + ((size_t)kh * HID + wv4 * 16 + l31) * 8;
    f16x8 wA0, wA1, wB0, wB1;
    {
        int kc = (wv4 + 4) & 31;
        const f16* wk = wbase + (size_t)kc * 8192;
        wA0 = *(const f16x8*)wk; wA1 = *(const f16x8*)(wk + 256);
    }
#pragma unroll 1
    for (int kp = 0; kp < 14; ++kp) {
        int j0 = 4 + 2 * kp;
        int kc1 = (wv4 + j0 + 1) & 31;
        {
            const f16* wk = wbase + (size_t)kc1 * 8192;
            wB0 = *(const f16x8*)wk; wB1 = *(const f16x8*)(wk + 256);
        }
        kc_mfma8(acc, act, wA0, wA1, (wv4 + j0) & 31, l31, kh);
        int kc2 = (wv4 + j0 + 2) & 31;  // kp==13 re-loads wv4 harmlessly
        {
            const f16* wk = wbase + (size_t)kc2 * 8192;
            wA0 = *(const f16x8*)wk; wA1 = *(const f16x8*)(wk + 256);
        }
        kc_mfma8(acc, act, wB0, wB1, kc1, l31, kh);
    }
}

__global__ __launch_bounds__(512, 2) void didi_main(
    const float* __restrict__ x1g,
    const float* __restrict__ b0g, const float* __restrict__ b1g,
    const float* __restrict__ b2g, const float* __restrict__ b3g,
    const float* __restrict__ b4g,
    const f16* __restrict__ wsp,
    float* __restrict__ outg) {
    __shared__ __align__(16) f16 act[BM * HID];        // 128 KB, in-place
    __shared__ __align__(16) float bias_lds[4 * HID];  // 8 KB

    const f16* W0p = wsp + OFF_W0;
    const f16* W1p = wsp + OFF_W1;
    const f16* W2p = wsp + OFF_W2;
    const f16* W3p = wsp + OFF_W3;
    const f16* W4p = wsp + OFF_W4;

    const int tid = threadIdx.x;
    const int wv = tid >> 6;   // wave 0..7
    const int ln = tid & 63;
    const int l31 = ln & 31;   // 32x32 lane row/col
    const int kh = ln >> 5;    // 32x32 k-half (0..1)
    const int lk = ln >> 4;    // 16x16 k-group 0..3 (L4 + update frame)
    const int lc = ln & 15;    // 16x16 col 0..15
    const int wv4 = wv * 4;    // rotation base (hidden layers)
    const int wv2 = wv * 2;    // rotation base (L4)
    const int rowBase = blockIdx.x * BM;

    // Stage biases L0-L3 into LDS (f32).
    for (int o = tid; o < HID; o += 512) {
        bias_lds[o] = b0g[o];
        bias_lds[HID + o] = b1g[o];
        bias_lds[2 * HID + o] = b2g[o];
        bias_lds[3 * HID + o] = b3g[o];
    }
    // L4 bias fragment: lane's 4 dims = lk*4+r.
    f32x4 bias4v = *(const f32x4*)(b4g + lk * 4);

    // Zero act once (padded W0 rows need 0 * finite).
    {
        f16x8 z = {};
        for (int o = tid; o < (BM * HID) / 8; o += 512)
            *(f16x8*)(act + o * 8) = z;
    }
    __syncthreads();

    // x-state: wave wv lane (lk,lc) holds row wv*16+lc, dims lk*4..+3 (dim-contiguous).
    f32x4 xr, x1r;
    {
        int grow = rowBase + wv * 16 + lc;
        x1r = *(const f32x4*)(x1g + grow * DIMS_X + lk * 4);
        xr = x1r;
        int lrow = wv * 16 + lc;
        f16x4 xf, x1f;
#pragma unroll
        for (int r = 0; r < 4; ++r) { xf[r] = (f16)xr[r]; x1f[r] = (f16)x1r[r]; }
        *(f16x4*)((char*)act + lds_off(lrow, lk * 8)) = xf;        // x_t cols 0-15
        *(f16x4*)((char*)act + lds_off(lrow, 32 + lk * 8)) = x1f;  // x_1 cols 16-31
        if (lk == 0)
            *(f16*)((char*)act + lds_off(lrow, 64)) = (f16)1.0f;   // t col 32
    }
    __syncthreads();

    const float dstep = -1.0f / 127.0f;
    f32x16 acc[2][4];
    f16x8 wE[8];

#pragma unroll 1
    for (int i = 0; i < NSTEPS; ++i) {
        // ---- L0 (K=64, 4 kc, no rotation: input written by all waves) ----
        init_acc(acc, bias_lds, wv, kh);
        {
            const f16* wbase = W0p + ((size_t)kh * HID + wv4 * 16 + l31) * 8;
#pragma unroll
            for (int kc = 0; kc < 4; ++kc) {
                const f16* wk = wbase + (size_t)kc * 8192;
                f16x8 w0 = *(const f16x8*)wk, w1 = *(const f16x8*)(wk + 256);
                kc_mfma8(acc, act, w0, w1, kc, l31, kh);
            }
        }
        __syncthreads();                         // mid0: all L0 reads done
        load_w4(wE, W1p, wv4, l31, kh);          // L1 early weights (shadowed by epi)
        epi_relu(acc, act, wv, l31, kh);         // write h0 (own cols)
        init_acc(acc, bias_lds + HID, wv, kh);
        early4(acc, act, wE, wv4, l31, kh);      // L1 on self-written cols
        __syncthreads();                         // end0
        hidden_main(acc, act, W1p, wv4, l31, kh);
        __syncthreads();                         // mid1
        load_w4(wE, W2p, wv4, l31, kh);
        epi_relu(acc, act, wv, l31, kh);
        init_acc(acc, bias_lds + 2 * HID, wv, kh);
        early4(acc, act, wE, wv4, l31, kh);
        __syncthreads();                         // end1
        hidden_main(acc, act, W2p, wv4, l31, kh);
        __syncthreads();                         // mid2
        load_w4(wE, W3p, wv4, l31, kh);
        epi_relu(acc, act, wv, l31, kh);
        init_acc(acc, bias_lds + 3 * HID, wv, kh);
        early4(acc, act, wE, wv4, l31, kh);
        __syncthreads();                         // end2
        hidden_main(acc, act, W3p, wv4, l31, kh);
        __syncthreads();                         // mid3
        epi_relu(acc, act, wv, l31, kh);         // write h3 (own cols)

        float t  = 1.0f + (float)i * dstep;
        float tp = (i == NSTEPS - 1) ? 0.0f : 1.0f + (float)(i + 1) * dstep;

        // ---- L4 early: own 2 of 16 kc (reads own rows x self-written cols) ----
        f32x4 acc4 = bias4v;
#pragma unroll
        for (int j = 0; j < 2; ++j) {
            int kc = wv2 + j;
            f16x8 w4fr = *(const f16x8*)(W4p + ((size_t)(kc * 4 + lk) * 16 + lc) * 8);
            f16x8 afr = *(const f16x8*)((const char*)act + lds_off(wv * 16 + lc, kc * 64 + lk * 16));
            acc4 = __builtin_amdgcn_mfma_f32_16x16x32_f16(w4fr, afr, acc4, 0, 0, 0);
        }
        __syncthreads();                         // end3: h3 complete everywhere
        // ---- L4 main: rotated j=2..15 ----
#pragma unroll
        for (int j = 2; j < 16; ++j) {
            int kc = wv2 + j; if (kc >= 16) kc -= 16;
            f16x8 w4fr = *(const f16x8*)(W4p + ((size_t)(kc * 4 + lk) * 16 + lc) * 8);
            f16x8 afr = *(const f16x8*)((const char*)act + lds_off(wv * 16 + lc, kc * 64 + lk * 16));
            acc4 = __builtin_amdgcn_mfma_f32_16x16x32_f16(w4fr, afr, acc4, 0, 0, 0);
        }
        {
            float ca = (t - tp) / t;
            float cb = tp / t;
            float sig = sqrtf(((0.01f * tp) * (t - tp)) / t);
            unsigned fk0, fk1;
            threefry2x32(0u, 42u, 0u, (unsigned)i, fk0, fk1);  // fold_in(key(42), i)
            int grow = rowBase + wv * 16 + lc;
            int lrow = wv * 16 + lc;
            f16x4 xf, x1f;
#pragma unroll
            for (int r = 0; r < 4; ++r) {
                float drift = acc4[r];  // bias pre-added
                unsigned flat = (unsigned)grow * 16u + (unsigned)(lk * 4 + r);
                // jax_threefry_partitionable: counter = (0, flat); draw = o0 ^ o1.
                unsigned o0, o1;
                threefry2x32(fk0, fk1, 0u, flat, o0, o1);
                unsigned bits = o0 ^ o1;
                float u01 = __uint_as_float((bits >> 9) | 0x3f800000u) - 1.0f;
                float u = u01 * 2.0f + (-0.99999994f);
                u = fmaxf(-0.99999994f, u);
                float nz = 1.4142135623730951f * erfinv_xla(u);
                float x = xr[r];
                float pred = x - t * drift;
                float xn = ca * pred + cb * x;
                xn = xn + sig * nz;
                xr[r] = xn;
                xf[r] = (f16)xn;
                x1f[r] = (f16)x1r[r];
            }
            // Re-stage next input (own rows only; same-wave DS order vs own L4 reads).
            *(f16x4*)((char*)act + lds_off(lrow, lk * 8)) = xf;
            *(f16x4*)((char*)act + lds_off(lrow, 32 + lk * 8)) = x1f;
            if (lk == 0)
                *(f16*)((char*)act + lds_off(lrow, 64)) = (f16)tp;
        }
        __syncthreads();                         // step barrier
    }

    {
        int grow = rowBase + wv * 16 + lc;
        *(f32x4*)(outg + grow * DIMS_X + lk * 4) = xr;
    }
}

extern "C" void kernel_launch(void* const* d_in, const int* in_sizes, int n_in,
                              void* d_out, int out_size, void* d_ws, size_t ws_size,
                              hipStream_t stream) {
    const float* x1 = (const float*)d_in[0];
    const float* w0 = (const float*)d_in[1];
    const float* b0 = (const float*)d_in[2];
    const float* w1 = (const float*)d_in[3];
    const float* b1 = (const float*)d_in[4];
    const float* w2 = (const float*)d_in[5];
    const float* b2 = (const float*)d_in[6];
    const float* w3 = (const float*)d_in[7];
    const float* b3 = (const float*)d_in[8];
    const float* w4 = (const float*)d_in[9];
    const float* b4 = (const float*)d_in[10];
    f16* ws = (f16*)d_ws;

    hipLaunchKernelGGL(pack_w0_kernel, dim3(128), dim3(256), 0, stream, w0, ws + OFF_W0);
    hipLaunchKernelGGL(pack_w_kernel, dim3(1024), dim3(256), 0, stream, w1, ws + OFF_W1, 512, 512, 512);
    hipLaunchKernelGGL(pack_w_kernel, dim3(1024), dim3(256), 0, stream, w2, ws + OFF_W2, 512, 512, 512);
    hipLaunchKernelGGL(pack_w_kernel, dim3(1024), dim3(256), 0, stream, w3, ws + OFF_W3, 512, 512, 512);
    hipLaunchKernelGGL(pack_w_kernel, dim3(32), dim3(256), 0, stream, w4, ws + OFF_W4, 512, 512, 16);

    hipLaunchKernelGGL(didi_main, dim3(BATCH / BM), dim3(512), 0, stream,
                       x1, b0, b1, b2, b3, b4, (const f16*)ws, (float*)d_out);
}

// Round 9
// 5705.002 us; speedup vs baseline: 1.8236x; 1.8236x over previous
//
#include <hip/hip_runtime.h>

typedef _Float16 f16;
typedef __attribute__((ext_vector_type(4))) _Float16 f16x4;
typedef __attribute__((ext_vector_type(8))) _Float16 f16x8;
typedef __attribute__((ext_vector_type(4))) float f32x4;

#define HID 512
#define DIMS_X 16
#define NSTEPS 127
#define BM 128
#define BATCH 32768
// Padded LDS row stride: 1040 B = 520 f16. Row r starts at bank (260r)%32 = 4r%32,
// so any 16-consecutive-row b128 fragment read is 2-way (free) without XOR swizzle,
// and addresses are purely additive (ds offset immediates fold, no per-access VALU).
#define LDST 520

// ws f16 layout offsets (elements)
#define OFF_W0 0
#define OFF_W1 32768
#define OFF_W2 (32768 + 262144)
#define OFF_W3 (32768 + 2 * 262144)
#define OFF_W4 (32768 + 3 * 262144)

// Pack f32 row-major [K][N] weights into f16 fragment-linear [Kpad/8][N][8].
__global__ void pack_w_kernel(const float* __restrict__ w, f16* __restrict__ out,
                              int K, int Kpad, int N) {
    int idx = blockIdx.x * blockDim.x + threadIdx.x;
    if (idx >= Kpad * N) return;
    int k = idx / N, n = idx - k * N;
    float v = (k < K) ? w[k * N + n] : 0.0f;
    out[(((k >> 3) * N) + n) * 8 + (k & 7)] = (f16)v;
}

// W0 pack with input-row permutation to the kernel's input layout:
// new rows 0-15 = x_t (orig rows 1..16), 16-31 = x_1 (orig 17..32), 32 = t (orig 0), 33-63 = 0.
__global__ void pack_w0_kernel(const float* __restrict__ w, f16* __restrict__ out) {
    int idx = blockIdx.x * blockDim.x + threadIdx.x;
    if (idx >= 64 * HID) return;
    int kn = idx / HID, n = idx - kn * HID;
    float v;
    if (kn < 32) v = w[(kn + 1) * HID + n];
    else if (kn == 32) v = w[n];
    else v = 0.0f;
    out[(((kn >> 3) * HID) + n) * 8 + (kn & 7)] = (f16)v;
}

__device__ __forceinline__ unsigned rotl32(unsigned x, int r) {
    return (x << r) | (x >> (32 - r));
}

// Threefry-2x32-20, matching jax._src.prng.threefry2x32 exactly.
__device__ __forceinline__ void threefry2x32(unsigned k0, unsigned k1,
                                             unsigned c0, unsigned c1,
                                             unsigned& o0, unsigned& o1) {
    unsigned ks2 = k0 ^ k1 ^ 0x1BD11BDAu;
    unsigned x0 = c0 + k0, x1 = c1 + k1;
#define TF_R(rot) { x0 += x1; x1 = rotl32(x1, rot); x1 ^= x0; }
    TF_R(13) TF_R(15) TF_R(26) TF_R(6)
    x0 += k1;  x1 += ks2 + 1u;
    TF_R(17) TF_R(29) TF_R(16) TF_R(24)
    x0 += ks2; x1 += k0 + 2u;
    TF_R(13) TF_R(15) TF_R(26) TF_R(6)
    x0 += k0;  x1 += k1 + 3u;
    TF_R(17) TF_R(29) TF_R(16) TF_R(24)
    x0 += k1;  x1 += ks2 + 4u;
    TF_R(13) TF_R(15) TF_R(26) TF_R(6)
    x0 += ks2; x1 += k0 + 5u;
#undef TF_R
    o0 = x0; o1 = x1;
}

// XLA's f32 ErfInv expansion (Giles polynomial).
__device__ __forceinline__ float erfinv_xla(float x) {
    float w = -log1pf(-x * x);
    float p;
    if (w < 5.0f) {
        w = w - 2.5f;
        p = 2.81022636e-08f;
        p = fmaf(p, w, 3.43273939e-07f);
        p = fmaf(p, w, -3.5233877e-06f);
        p = fmaf(p, w, -4.39150654e-06f);
        p = fmaf(p, w, 0.00021858087f);
        p = fmaf(p, w, -0.00125372503f);
        p = fmaf(p, w, -0.00417768164f);
        p = fmaf(p, w, 0.246640727f);
        p = fmaf(p, w, 1.50140941f);
    } else {
        w = sqrtf(w) - 3.0f;
        p = -0.000200214257f;
        p = fmaf(p, w, 0.000100950558f);
        p = fmaf(p, w, 0.00134934322f);
        p = fmaf(p, w, -0.00367342844f);
        p = fmaf(p, w, 0.00573950773f);
        p = fmaf(p, w, -0.0076224613f);
        p = fmaf(p, w, 0.00943887047f);
        p = fmaf(p, w, 1.00167406f);
        p = fmaf(p, w, 2.83297682f);
    }
    return p * x;
}

// LDS byte offset on the padded [BM][520] f16 tile (no swizzle, purely additive).
__device__ __forceinline__ unsigned lds_off(int row, int colByte) {
    return (unsigned)(row * (LDST * 2) + colByte);
}

// One kc sub-step: MFMA 4x8 tiles with `wc` (current W frags), prefetch kc+1's
// W frags into `wn`. Named cur/nxt sets (no runtime indexing -> stays in regs).
#define KC_BODY(kc, wc, wn, NKC)                                                      \
    {                                                                                 \
        if ((kc) + 1 < (NKC)) {                                                       \
            const f16* wk = wbase + (size_t)((kc) + 1) * (4 * HID * 8);               \
            wn[0] = *(const f16x8*)(wk);                                              \
            wn[1] = *(const f16x8*)(wk + 128);                                        \
            wn[2] = *(const f16x8*)(wk + 256);                                        \
            wn[3] = *(const f16x8*)(wk + 384);                                        \
        }                                                                             \
        f16x8 afr[8];                                                                 \
        _Pragma("unroll")                                                             \
        for (int tb = 0; tb < 8; ++tb)                                                \
            afr[tb] = *(const f16x8*)((const char*)act +                              \
                                      lds_off(tb * 16 + lc, (kc) * 64 + lk * 16));    \
        _Pragma("unroll")                                                             \
        for (int tn = 0; tn < 4; ++tn)                                                \
            _Pragma("unroll")                                                         \
            for (int tb = 0; tb < 8; ++tb)                                            \
                acc[tn][tb] = __builtin_amdgcn_mfma_f32_16x16x32_f16(                 \
                    wc[tn], afr[tb], acc[tn][tb], 0, 0, 0);                           \
    }

// One hidden layer, operand-swapped (D = W^T * X^T), in-place on `act`.
// Wave wv owns output cols n = wv*64..+63 for ALL 128 batch rows.
template <int NKC>
__device__ __forceinline__ void layer_swapped(f16* act, const f16* __restrict__ Wp,
                                              const float* bias_l,
                                              int wv, int lk, int lc) {
    f32x4 acc[4][8];
#pragma unroll
    for (int tn = 0; tn < 4; ++tn) {
        f32x4 bv = *(const f32x4*)(bias_l + wv * 64 + tn * 16 + lk * 4);
#pragma unroll
        for (int tb = 0; tb < 8; ++tb) acc[tn][tb] = bv;
    }

    const f16* wbase = Wp + ((size_t)lk * HID + wv * 64 + lc) * 8;
    f16x8 wA[4], wB[4];
    wA[0] = *(const f16x8*)(wbase);
    wA[1] = *(const f16x8*)(wbase + 128);
    wA[2] = *(const f16x8*)(wbase + 256);
    wA[3] = *(const f16x8*)(wbase + 384);

#pragma unroll 1
    for (int kp = 0; kp < NKC / 2; ++kp) {
        KC_BODY(2 * kp, wA, wB, NKC)
        KC_BODY(2 * kp + 1, wB, wA, NKC)
    }

    __syncthreads();  // all reads of act complete -> safe to overwrite
    // D frag: col=lane&15 -> batch row; row=(lane>>4)*4+r -> 4 CONSECUTIVE hidden cols.
#pragma unroll
    for (int tn = 0; tn < 4; ++tn)
#pragma unroll
        for (int tb = 0; tb < 8; ++tb) {
            f16x4 v;
#pragma unroll
            for (int r = 0; r < 4; ++r) v[r] = (f16)fmaxf(acc[tn][tb][r], 0.0f);
            int brow = tb * 16 + lc;
            int nb = (wv * 64 + tn * 16 + lk * 4) * 2;
            *(f16x4*)((char*)act + lds_off(brow, nb)) = v;  // ds_write_b64
        }
    __syncthreads();
}

__global__ __launch_bounds__(512, 2) void didi_main(
    const float* __restrict__ x1g,
    const float* __restrict__ b0g, const float* __restrict__ b1g,
    const float* __restrict__ b2g, const float* __restrict__ b3g,
    const float* __restrict__ b4g,
    const f16* __restrict__ wsp,
    float* __restrict__ outg) {
    __shared__ __align__(16) f16 act[BM * LDST];       // 130 KB padded, in-place
    __shared__ __align__(16) float bias_lds[4 * HID];  // 8 KB

    const f16* W0p = wsp + OFF_W0;
    const f16* W1p = wsp + OFF_W1;
    const f16* W2p = wsp + OFF_W2;
    const f16* W3p = wsp + OFF_W3;
    const f16* W4p = wsp + OFF_W4;

    const int tid = threadIdx.x;
    const int wv = tid >> 6;   // wave 0..7
    const int ln = tid & 63;
    const int lk = ln >> 4;    // 0..3
    const int lc = ln & 15;    // 0..15
    const int rowBase = blockIdx.x * BM;

    // Stage biases L0-L3 into LDS (f32).
    for (int o = tid; o < HID; o += 512) {
        bias_lds[o] = b0g[o];
        bias_lds[HID + o] = b1g[o];
        bias_lds[2 * HID + o] = b2g[o];
        bias_lds[3 * HID + o] = b3g[o];
    }
    // L4 bias fragment: lane's 4 dims = lk*4+r.
    f32x4 bias4v = *(const f32x4*)(b4g + lk * 4);

    // Zero act once (padded W0 rows need 0 * finite; pads included, 520%8==0).
    {
        f16x8 z = {};
        for (int o = tid; o < (BM * LDST) / 8; o += 512)
            *(f16x8*)(act + o * 8) = z;
    }
    __syncthreads();

    // x-state: wave wv lane (lk,lc) holds row wv*16+lc, dims lk*4..+3 (dim-contiguous).
    f32x4 xr, x1r;
    {
        int grow = rowBase + wv * 16 + lc;
        x1r = *(const f32x4*)(x1g + grow * DIMS_X + lk * 4);
        xr = x1r;
        int lrow = wv * 16 + lc;
        f16x4 xf, x1f;
#pragma unroll
        for (int r = 0; r < 4; ++r) { xf[r] = (f16)xr[r]; x1f[r] = (f16)x1r[r]; }
        *(f16x4*)((char*)act + lds_off(lrow, lk * 8)) = xf;        // x_t cols 0-15
        *(f16x4*)((char*)act + lds_off(lrow, 32 + lk * 8)) = x1f;  // x_1 cols 16-31
        if (lk == 0)
            *(f16*)((char*)act + lds_off(lrow, 64)) = (f16)1.0f;   // t col 32
    }
    __syncthreads();

    const float dstep = -1.0f / 127.0f;

#pragma unroll 1
    for (int i = 0; i < NSTEPS; ++i) {
        layer_swapped<2>(act, W0p, bias_lds, wv, lk, lc);
        layer_swapped<16>(act, W1p, bias_lds + HID, wv, lk, lc);
        layer_swapped<16>(act, W2p, bias_lds + 2 * HID, wv, lk, lc);
        layer_swapped<16>(act, W3p, bias_lds + 3 * HID, wv, lk, lc);

        float t  = 1.0f + (float)i * dstep;
        float tp = (i == NSTEPS - 1) ? 0.0f : 1.0f + (float)(i + 1) * dstep;

        {
            // L4 (16x16x32): each wave computes 16 dims x its own 16 rows, K=512.
            f32x4 acc4 = bias4v;
#pragma unroll 4
            for (int kc = 0; kc < 16; ++kc) {
                f16x8 w4fr = *(const f16x8*)(W4p + ((size_t)(kc * 4 + lk) * 16 + lc) * 8);
                f16x8 afr = *(const f16x8*)((const char*)act + lds_off(wv * 16 + lc, kc * 64 + lk * 16));
                acc4 = __builtin_amdgcn_mfma_f32_16x16x32_f16(w4fr, afr, acc4, 0, 0, 0);
            }
            float ca = (t - tp) / t;
            float cb = tp / t;
            float sig = sqrtf(((0.01f * tp) * (t - tp)) / t);
            unsigned fk0, fk1;
            threefry2x32(0u, 42u, 0u, (unsigned)i, fk0, fk1);  // fold_in(key(42), i)
            int grow = rowBase + wv * 16 + lc;
            int lrow = wv * 16 + lc;
            f16x4 xf, x1f;
#pragma unroll
            for (int r = 0; r < 4; ++r) {
                float drift = acc4[r];  // bias pre-added
                unsigned flat = (unsigned)grow * 16u + (unsigned)(lk * 4 + r);
                // jax_threefry_partitionable: counter = (0, flat); draw = o0 ^ o1.
                unsigned o0, o1;
                threefry2x32(fk0, fk1, 0u, flat, o0, o1);
                unsigned bits = o0 ^ o1;
                float u01 = __uint_as_float((bits >> 9) | 0x3f800000u) - 1.0f;
                float u = u01 * 2.0f + (-0.99999994f);
                u = fmaxf(-0.99999994f, u);
                float nz = 1.4142135623730951f * erfinv_xla(u);
                float x = xr[r];
                float pred = x - t * drift;
                float xn = ca * pred + cb * x;
                xn = xn + sig * nz;
                xr[r] = xn;
                xf[r] = (f16)xn;
                x1f[r] = (f16)x1r[r];
            }
            // Re-stage next input over cols 0-32 (own rows only; per-wave DS order makes
            // this safe w.r.t. this wave's L4 reads). Cols 33-63 hold finite h3 garbage
            // which meets exact-zero padded W0 rows -> contributes 0.
            *(f16x4*)((char*)act + lds_off(lrow, lk * 8)) = xf;
            *(f16x4*)((char*)act + lds_off(lrow, 32 + lk * 8)) = x1f;
            if (lk == 0)
                *(f16*)((char*)act + lds_off(lrow, 64)) = (f16)tp;
        }
        __syncthreads();
    }

    {
        int grow = rowBase + wv * 16 + lc;
        *(f32x4*)(outg + grow * DIMS_X + lk * 4) = xr;
    }
}

extern "C" void kernel_launch(void* const* d_in, const int* in_sizes, int n_in,
                              void* d_out, int out_size, void* d_ws, size_t ws_size,
                              hipStream_t stream) {
    const float* x1 = (const float*)d_in[0];
    const float* w0 = (const float*)d_in[1];
    const float* b0 = (const float*)d_in[2];
    const float* w1 = (const float*)d_in[3];
    const float* b1 = (const float*)d_in[4];
    const float* w2 = (const float*)d_in[5];
    const float* b2 = (const float*)d_in[6];
    const float* w3 = (const float*)d_in[7];
    const float* b3 = (const float*)d_in[8];
    const float* w4 = (const float*)d_in[9];
    const float* b4 = (const float*)d_in[10];
    f16* ws = (f16*)d_ws;

    hipLaunchKernelGGL(pack_w0_kernel, dim3(128), dim3(256), 0, stream, w0, ws + OFF_W0);
    hipLaunchKernelGGL(pack_w_kernel, dim3(1024), dim3(256), 0, stream, w1, ws + OFF_W1, 512, 512, 512);
    hipLaunchKernelGGL(pack_w_kernel, dim3(1024), dim3(256), 0, stream, w2, ws + OFF_W2, 512, 512, 512);
    hipLaunchKernelGGL(pack_w_kernel, dim3(1024), dim3(256), 0, stream, w3, ws + OFF_W3, 512, 512, 512);
    hipLaunchKernelGGL(pack_w_kernel, dim3(32), dim3(256), 0, stream, w4, ws + OFF_W4, 512, 512, 16);

    hipLaunchKernelGGL(didi_main, dim3(BATCH / BM), dim3(512), 0, stream,
                       x1, b0, b1, b2, b3, b4, (const f16*)ws, (float*)d_out);
}